// Round 2
// baseline (651.113 us; speedup 1.0000x reference)
//
#include <hip/hip_runtime.h>
#include <math.h>

// Problem constants (fixed by reference: b=4, n=2048, d=1024, H=16, DH=64)
#define BB    4
#define NN    2048
#define DD    1024
#define HH    16
#define DHD   64
#define INNER 1024
// log2(10000)/16 for inv_freq = 2^(-f * LOG2_10K_D16)
#define LOG2_10K_D16 0.8304820237218406f
// SCALE * log2(e): folded into Q at projection time -> attn uses raw exp2
#define SCALE_LOG2E 0.1803368801111601f

typedef short bf16x8 __attribute__((ext_vector_type(8)));   // 8 bf16 = 4 VGPRs
typedef float f32x4  __attribute__((ext_vector_type(4)));
typedef unsigned short u16x8 __attribute__((ext_vector_type(8)));

// async 16B/lane global->LDS (lane i lands at wave-uniform base + i*16)
#define ASYNC16(g, l) __builtin_amdgcn_global_load_lds( \
    (const __attribute__((address_space(1))) void*)(g),  \
    (__attribute__((address_space(3))) void*)(l), 16, 0, 0)

// ---------- fast exp2: raw v_exp_f32, no libm range guard ----------
static __device__ __forceinline__ float fexp2(float x) {
#if __has_builtin(__builtin_amdgcn_exp2f)
    return __builtin_amdgcn_exp2f(x);
#else
    float r;
    asm("v_exp_f32 %0, %1" : "=v"(r) : "v"(x));
    return r;
#endif
}

// ---------- bf16 helpers (manual RNE; no hip_bf16.h dependency) ----------
static __device__ __forceinline__ unsigned short f2bf(float f) {
    union { float f; unsigned int u; } v; v.f = f;
    unsigned int u = v.u;
    u += 0x7fffu + ((u >> 16) & 1u);
    return (unsigned short)(u >> 16);
}
// pack two f32 -> bf16x2 dword, round-half-up via +0x8000 then byte-perm.
static __device__ __forceinline__ unsigned int packbf2(float lo, float hi) {
    union { float f; unsigned int u; } a, b;
    a.f = lo; b.f = hi;
    return __builtin_amdgcn_perm(b.u + 0x8000u, a.u + 0x8000u, 0x07060302u);
}

// =====================================================================
// Pre-pass A: cast X fp32 -> bf16
// =====================================================================
__global__ __launch_bounds__(256) void cast_x_kernel(
    const float* __restrict__ X, unsigned short* __restrict__ Xb)
{
    const size_t i = ((size_t)blockIdx.x * 256 + threadIdx.x) * 8;
    const float4 a = *(const float4*)(X + i);
    const float4 b = *(const float4*)(X + i + 4);
    u16x8 o;
    o[0] = f2bf(a.x); o[1] = f2bf(a.y); o[2] = f2bf(a.z); o[3] = f2bf(a.w);
    o[4] = f2bf(b.x); o[5] = f2bf(b.y); o[6] = f2bf(b.z); o[7] = f2bf(b.w);
    *(u16x8*)(Xb + i) = o;
}

// =====================================================================
// Pre-pass B: transpose-cast W [K][N] fp32 -> Wt [N][K] bf16
// =====================================================================
__global__ __launch_bounds__(256) void tcast_kernel(
    const float* __restrict__ src, unsigned short* __restrict__ dst,
    int K, int N)
{
    __shared__ float ts[32][33];
    const int t = threadIdx.x;
    const int n0 = blockIdx.x * 32, k0 = blockIdx.y * 32;
    const int r = t >> 5, c = t & 31;
    #pragma unroll
    for (int p = 0; p < 4; ++p)
        ts[r + p * 8][c] = src[(size_t)(k0 + r + p * 8) * N + n0 + c];
    __syncthreads();
    #pragma unroll
    for (int p = 0; p < 4; ++p)
        dst[(size_t)(n0 + r + p * 8) * K + k0 + c] = f2bf(ts[c][r + p * 8]);
}

// =====================================================================
// Kernel 1: QKV projection via bf16 MFMA + fused RoPE + head-split.
// =====================================================================
__global__ __launch_bounds__(256) void proj_qkv_mfma(
    const unsigned short* __restrict__ Xb, const unsigned short* __restrict__ Wt,
    unsigned short* __restrict__ qb, unsigned short* __restrict__ kb,
    unsigned short* __restrict__ vb)
{
    __shared__ __align__(16) unsigned short As[128 * 32];
    __shared__ __align__(16) unsigned short Bs[128 * 32];

    const int t     = threadIdx.x;
    const int w     = t >> 6, lane = t & 63;
    const int lane4 = lane & 15, quad = lane >> 4, quad8 = quad * 8;
    const int wm    = w >> 1, wn = w & 1;
    const int m0    = blockIdx.y * 128, n0 = blockIdx.x * 128;

    const int srow = t >> 2, scol = (t & 3) * 8;
    const unsigned short* gA = Xb + (size_t)(m0 + srow) * DD + scol;
    const unsigned short* gB = Wt + (size_t)(n0 + srow) * DD + scol;
    unsigned short* lA = As + t * 8;
    unsigned short* lB = Bs + t * 8;

    f32x4 acc[4][4] = {};

    for (int k0 = 0; k0 < DD; k0 += 32) {
        __syncthreads();
        ASYNC16(gA + k0,            lA);
        ASYNC16(gA + 64 * DD + k0,  lA + 2048);
        ASYNC16(gB + k0,            lB);
        ASYNC16(gB + 64 * DD + k0,  lB + 2048);
        __syncthreads();

        bf16x8 a[4], b[4];
        #pragma unroll
        for (int i = 0; i < 4; ++i)
            a[i] = *(const bf16x8*)&As[(wm * 64 + i * 16 + lane4) * 32 + quad8];
        #pragma unroll
        for (int j = 0; j < 4; ++j)
            b[j] = *(const bf16x8*)&Bs[(wn * 64 + j * 16 + lane4) * 32 + quad8];
        #pragma unroll
        for (int i = 0; i < 4; ++i)
            #pragma unroll
            for (int j = 0; j < 4; ++j)
                acc[i][j] = __builtin_amdgcn_mfma_f32_16x16x32_bf16(
                    a[i], b[j], acc[i][j], 0, 0, 0);
    }

    // ---- epilogue ----
    const int sec = n0 >> 10;                  // 0=q 1=k 2=v (uniform/block)

    if (sec == 2) {
        // V: transposed global layout, 4 consecutive n per lane -> uint2
        #pragma unroll
        for (int j = 0; j < 4; ++j) {
            const int csec = (n0 & 1023) + wn * 64 + j * 16;
            const int h    = csec >> 6;
            const int dh   = (csec & 63) + lane4;
            #pragma unroll
            for (int i = 0; i < 4; ++i) {
                const int rg0 = m0 + wm * 64 + i * 16 + quad * 4;
                const int b   = rg0 >> 11;
                const int n   = rg0 & 2047;
                uint2 pk;
                pk.x = packbf2(acc[i][j][0], acc[i][j][1]);
                pk.y = packbf2(acc[i][j][2], acc[i][j][3]);
                *(uint2*)(vb + (((size_t)b * HH + h) * DHD + dh) * NN + n) = pk;
            }
        }
    } else {
        unsigned short* dst = (sec == 0) ? qb : kb;
        const float qscale = (sec == 0) ? SCALE_LOG2E : 1.0f;
        #pragma unroll
        for (int j = 0; j < 4; ++j) {
            const int csec = (n0 & 1023) + wn * 64 + j * 16;
            const int h    = csec >> 6;
            const int dhb  = csec & 63;
            const int dh   = dhb + lane4;
            const bool rope = (dhb < 32);          // wave-uniform
            const float invf = fexp2(-(float)(dh >> 1) * LOG2_10K_D16);
            #pragma unroll
            for (int i = 0; i < 4; ++i) {
                #pragma unroll
                for (int r = 0; r < 4; ++r) {
                    const int rg = m0 + wm * 64 + i * 16 + quad * 4 + r;
                    const int b  = rg >> 11;
                    const int n  = rg & 2047;
                    float x = acc[i][j][r] * qscale;
                    if (rope) {
                        const float ang = (float)n * invf;
                        float s_, c_;
                        __sincosf(ang, &s_, &c_);
                        const float p = __shfl_xor(x, 1);
                        x = (lane4 & 1) ? fmaf(p, s_, x * c_)
                                        : fmaf(p, -s_, x * c_);
                    }
                    dst[(((size_t)b * HH + h) * NN + n) * DHD + dh] = f2bf(x);
                }
            }
        }
    }
}

// =====================================================================
// Kernel 2: flash attention, S^T formulation, max-free softmax.
// NO K/V LDS staging: the QK^T A-fragment pattern [key][dh] IS the
// global layout of kb, and the PV A-fragment [dh][key] IS the global
// layout of vtb -- fragments load DIRECTLY from global. All 4 waves
// read identical addresses (L1 broadcast); all 32 q-tile blocks of a
// head share one XCD (id%8 == bh%8), so K/V stay L2-resident (R1:
// FETCH_SIZE 46 MB proved locality). Zero barriers in the main loop;
// only the wave-local pst LDS buffer remains (9 KB -> occupancy up).
// =====================================================================
__global__ __launch_bounds__(256) void attn_kernel(
    const unsigned short* __restrict__ qb, const unsigned short* __restrict__ kb,
    const unsigned short* __restrict__ vtb, unsigned short* __restrict__ aob)
{
    __shared__ __align__(16) unsigned short pst[4][16][72];  // per-wave P^T

    const int t     = threadIdx.x;
    const int w     = t >> 6;
    const int lane  = t & 63;
    const int lane4 = lane & 15;
    const int quad  = lane >> 4;
    const int quad8 = quad * 8;

    const int bid = blockIdx.x;
    const int bh  = bid & 63;          // id%8 = bh%8 -> per-XCD head groups
    const int q0  = (bid >> 6) * 64;
    const size_t hb = (size_t)bh * NN * DHD;

    // Q B-fragments (registers, whole kernel): B[n=q=lane4][k=dh quad8+j]
    const unsigned short* qrow = qb + hb + (size_t)(q0 + w * 16 + lane4) * DHD;
    const bf16x8 qf0 = *(const bf16x8*)(qrow + quad8);
    const bf16x8 qf1 = *(const bf16x8*)(qrow + 32 + quad8);

    // ones A-fragment for the l-accumulating MFMA
    bf16x8 onesf;
    #pragma unroll
    for (int j = 0; j < 8; ++j) onesf[j] = (short)0x3F80;

    // per-lane direct-from-global fragment bases
    // K: row = key = kt*64 + c*16 + lane4, col = dh quad8 (+32 for hi half)
    // V: row = dh  = c*16 + lane4,        col = key kt*64 + quad8 (+32)
    const unsigned short* kbase = kb  + hb + (size_t)lane4 * DHD + quad8;
    const unsigned short* vbase = vtb + hb + (size_t)lane4 * NN  + quad8;

    f32x4 o[4], lacc;
    #pragma unroll
    for (int c = 0; c < 4; ++c) o[c] = (f32x4){0.f, 0.f, 0.f, 0.f};
    lacc = (f32x4){0.f, 0.f, 0.f, 0.f};

    for (int kt = 0; kt < NN / 64; ++kt) {
        const unsigned short* kp = kbase + (size_t)kt * 64 * DHD;
        const unsigned short* vp = vbase + kt * 64;

        // fragment loads straight from global (L1/L2-served)
        bf16x8 ka[4][2], va[4][2];
        #pragma unroll
        for (int c = 0; c < 4; ++c) {
            ka[c][0] = *(const bf16x8*)(kp + c * 16 * DHD);
            ka[c][1] = *(const bf16x8*)(kp + c * 16 * DHD + 32);
            va[c][0] = *(const bf16x8*)(vp + (size_t)c * 16 * NN);
            va[c][1] = *(const bf16x8*)(vp + (size_t)c * 16 * NN + 32);
        }

        // ---- S^T = K Q^T : 4 key-tiles, each K=64 over dh ----
        f32x4 sc[4];
        #pragma unroll
        for (int c = 0; c < 4; ++c) {
            f32x4 z = (f32x4){0.f, 0.f, 0.f, 0.f};
            z = __builtin_amdgcn_mfma_f32_16x16x32_bf16(ka[c][0], qf0, z, 0, 0, 0);
            z = __builtin_amdgcn_mfma_f32_16x16x32_bf16(ka[c][1], qf1, z, 0, 0, 0);
            sc[c] = z;   // (key = c*16 + quad*4 + r, q = lane4)
        }

        // ---- max-free softmax numerators: p = exp2(sc), pack, store ----
        #pragma unroll
        for (int c = 0; c < 4; ++c) {
            const float p0 = fexp2(sc[c][0]);
            const float p1 = fexp2(sc[c][1]);
            const float p2 = fexp2(sc[c][2]);
            const float p3 = fexp2(sc[c][3]);
            uint2 pk;
            pk.x = packbf2(p0, p1);
            pk.y = packbf2(p2, p3);
            *(uint2*)&pst[w][lane4][c * 16 + quad * 4] = pk;
        }

        // ---- P^T B-fragments (wave-local LDS, no barrier) ----
        const bf16x8 pf0 = *(const bf16x8*)&pst[w][lane4][quad8];        // keys 0..31
        const bf16x8 pf1 = *(const bf16x8*)&pst[w][lane4][32 + quad8];   // keys 32..63

        // ---- O^T += V^T P^T ; l += ones P^T ----
        #pragma unroll
        for (int c = 0; c < 4; ++c) {
            o[c] = __builtin_amdgcn_mfma_f32_16x16x32_bf16(va[c][0], pf0, o[c], 0, 0, 0);
            o[c] = __builtin_amdgcn_mfma_f32_16x16x32_bf16(va[c][1], pf1, o[c], 0, 0, 0);
        }
        lacc = __builtin_amdgcn_mfma_f32_16x16x32_bf16(onesf, pf0, lacc, 0, 0, 0);
        lacc = __builtin_amdgcn_mfma_f32_16x16x32_bf16(onesf, pf1, lacc, 0, 0, 0);
    }

    // ---- epilogue: O^T (dh=c*16+quad*4+r, q=lane4), lane-local normalize ----
    const int b = bh >> 4, h = bh & 15;
    const float linv = 1.0f / lacc[0];
    const int n = q0 + w * 16 + lane4;
    unsigned short* obase = aob + ((size_t)b * NN + n) * INNER + h * DHD;
    #pragma unroll
    for (int c = 0; c < 4; ++c) {
        uint2 pk;
        pk.x = packbf2(o[c][0] * linv, o[c][1] * linv);
        pk.y = packbf2(o[c][2] * linv, o[c][3] * linv);
        *(uint2*)(obase + c * 16 + quad * 4) = pk;
    }
}

// =====================================================================
// Kernel 3: output projection via bf16 MFMA.
// =====================================================================
__global__ __launch_bounds__(256) void out_proj_mfma(
    const unsigned short* __restrict__ Ab, const unsigned short* __restrict__ Wt,
    const float* __restrict__ bias, float* __restrict__ C)
{
    __shared__ __align__(16) unsigned short As[128 * 32];
    __shared__ __align__(16) unsigned short Bs[128 * 32];

    const int t     = threadIdx.x;
    const int w     = t >> 6, lane = t & 63;
    const int lane4 = lane & 15, quad = lane >> 4, quad8 = quad * 8;
    const int wm    = w >> 1, wn = w & 1;
    const int m0    = blockIdx.y * 128, n0 = blockIdx.x * 128;

    const int srow = t >> 2, scol = (t & 3) * 8;
    const unsigned short* gA = Ab + (size_t)(m0 + srow) * INNER + scol;
    const unsigned short* gB = Wt + (size_t)(n0 + srow) * INNER + scol;
    unsigned short* lA = As + t * 8;
    unsigned short* lB = Bs + t * 8;

    f32x4 acc[4][4] = {};

    for (int k0 = 0; k0 < INNER; k0 += 32) {
        __syncthreads();
        ASYNC16(gA + k0,               lA);
        ASYNC16(gA + 64 * INNER + k0,  lA + 2048);
        ASYNC16(gB + k0,               lB);
        ASYNC16(gB + 64 * INNER + k0,  lB + 2048);
        __syncthreads();

        bf16x8 a[4], b[4];
        #pragma unroll
        for (int i = 0; i < 4; ++i)
            a[i] = *(const bf16x8*)&As[(wm * 64 + i * 16 + lane4) * 32 + quad8];
        #pragma unroll
        for (int j = 0; j < 4; ++j)
            b[j] = *(const bf16x8*)&Bs[(wn * 64 + j * 16 + lane4) * 32 + quad8];
        #pragma unroll
        for (int i = 0; i < 4; ++i)
            #pragma unroll
            for (int j = 0; j < 4; ++j)
                acc[i][j] = __builtin_amdgcn_mfma_f32_16x16x32_bf16(
                    a[i], b[j], acc[i][j], 0, 0, 0);
    }

    #pragma unroll
    for (int j = 0; j < 4; ++j) {
        const int col = n0 + wn * 64 + j * 16 + lane4;
        const float bv = bias[col];
        #pragma unroll
        for (int i = 0; i < 4; ++i)
            #pragma unroll
            for (int r = 0; r < 4; ++r) {
                const int rg = m0 + wm * 64 + i * 16 + quad * 4 + r;
                C[(size_t)rg * DD + col] = acc[i][j][r] + bv;
            }
    }
}

// =====================================================================
extern "C" void kernel_launch(void* const* d_in, const int* in_sizes, int n_in,
                              void* d_out, int out_size, void* d_ws, size_t ws_size,
                              hipStream_t stream)
{
    const float* X    = (const float*)d_in[0];   // (4,2048,1024)
    const float* Wq   = (const float*)d_in[1];   // (1024,1024)
    const float* Wkv  = (const float*)d_in[2];   // (1024,2048)
    const float* Wout = (const float*)d_in[3];   // (1024,1024)
    const float* bout = (const float*)d_in[4];   // (1024,)
    float* out = (float*)d_out;

    // ws (bf16 elems): qb|kb|vtb|xb(=aob after proj)|WtAll|WoT = 75.5 MB
    const size_t E = (size_t)BB * HH * NN * DHD;   // 8388608
    unsigned short* qb  = (unsigned short*)d_ws;
    unsigned short* kb  = qb + E;
    unsigned short* vtb = kb + E;                // V^T [b][h][dh][n]
    unsigned short* xb  = vtb + E;               // X bf16; later reused as ao
    unsigned short* wt  = xb + E;                // [3072][1024] = WqT ; WkvT
    unsigned short* wo  = wt + (size_t)3072 * 1024;  // [1024][1024]

    cast_x_kernel<<<4096, 256, 0, stream>>>(X, xb);
    tcast_kernel<<<dim3(32, 32), 256, 0, stream>>>(Wq,   wt,               1024, 1024);
    tcast_kernel<<<dim3(64, 32), 256, 0, stream>>>(Wkv,  wt + 1024 * 1024, 1024, 2048);
    tcast_kernel<<<dim3(32, 32), 256, 0, stream>>>(Wout, wo,               1024, 1024);

    proj_qkv_mfma<<<dim3(3072 / 128, 8192 / 128), 256, 0, stream>>>(
        xb, wt, qb, kb, vtb);

    attn_kernel<<<dim3(NN / 64 * BB * HH), 256, 0, stream>>>(qb, kb, vtb, xb);

    out_proj_mfma<<<dim3(1024 / 128, 8192 / 128), 256, 0, stream>>>(
        xb, wo, bout, out);
}

// Round 3
// 322.338 us; speedup vs baseline: 2.0200x; 2.0200x over previous
//
#include <hip/hip_runtime.h>
#include <math.h>

// Problem constants (fixed by reference: b=4, n=2048, d=1024, H=16, DH=64)
#define BB    4
#define NN    2048
#define DD    1024
#define HH    16
#define DHD   64
#define INNER 1024
// log2(10000)/16 for inv_freq = 2^(-f * LOG2_10K_D16)
#define LOG2_10K_D16 0.8304820237218406f
// SCALE * log2(e): folded into Q at projection time -> attn uses raw exp2
#define SCALE_LOG2E 0.1803368801111601f

typedef short bf16x8 __attribute__((ext_vector_type(8)));   // 8 bf16 = 4 VGPRs
typedef float f32x4  __attribute__((ext_vector_type(4)));
typedef unsigned short u16x8 __attribute__((ext_vector_type(8)));

// async 16B/lane global->LDS (lane i lands at wave-uniform base + i*16)
#define ASYNC16(g, l) __builtin_amdgcn_global_load_lds( \
    (const __attribute__((address_space(1))) void*)(g),  \
    (__attribute__((address_space(3))) void*)(l), 16, 0, 0)

// ---------- fast exp2: raw v_exp_f32, no libm range guard ----------
static __device__ __forceinline__ float fexp2(float x) {
#if __has_builtin(__builtin_amdgcn_exp2f)
    return __builtin_amdgcn_exp2f(x);
#else
    float r;
    asm("v_exp_f32 %0, %1" : "=v"(r) : "v"(x));
    return r;
#endif
}

// ---------- bf16 helpers (manual RNE; no hip_bf16.h dependency) ----------
static __device__ __forceinline__ unsigned short f2bf(float f) {
    union { float f; unsigned int u; } v; v.f = f;
    unsigned int u = v.u;
    u += 0x7fffu + ((u >> 16) & 1u);
    return (unsigned short)(u >> 16);
}
// pack two f32 -> bf16x2 dword, round-half-up via +0x8000 then byte-perm.
static __device__ __forceinline__ unsigned int packbf2(float lo, float hi) {
    union { float f; unsigned int u; } a, b;
    a.f = lo; b.f = hi;
    return __builtin_amdgcn_perm(b.u + 0x8000u, a.u + 0x8000u, 0x07060302u);
}

// =====================================================================
// Pre-pass A: cast X fp32 -> bf16
// =====================================================================
__global__ __launch_bounds__(256) void cast_x_kernel(
    const float* __restrict__ X, unsigned short* __restrict__ Xb)
{
    const size_t i = ((size_t)blockIdx.x * 256 + threadIdx.x) * 8;
    const float4 a = *(const float4*)(X + i);
    const float4 b = *(const float4*)(X + i + 4);
    u16x8 o;
    o[0] = f2bf(a.x); o[1] = f2bf(a.y); o[2] = f2bf(a.z); o[3] = f2bf(a.w);
    o[4] = f2bf(b.x); o[5] = f2bf(b.y); o[6] = f2bf(b.z); o[7] = f2bf(b.w);
    *(u16x8*)(Xb + i) = o;
}

// =====================================================================
// Pre-pass B: transpose-cast W [K][N] fp32 -> Wt [N][K] bf16
// =====================================================================
__global__ __launch_bounds__(256) void tcast_kernel(
    const float* __restrict__ src, unsigned short* __restrict__ dst,
    int K, int N)
{
    __shared__ float ts[32][33];
    const int t = threadIdx.x;
    const int n0 = blockIdx.x * 32, k0 = blockIdx.y * 32;
    const int r = t >> 5, c = t & 31;
    #pragma unroll
    for (int p = 0; p < 4; ++p)
        ts[r + p * 8][c] = src[(size_t)(k0 + r + p * 8) * N + n0 + c];
    __syncthreads();
    #pragma unroll
    for (int p = 0; p < 4; ++p)
        dst[(size_t)(n0 + r + p * 8) * K + k0 + c] = f2bf(ts[c][r + p * 8]);
}

// =====================================================================
// Kernel 1: QKV projection via bf16 MFMA + fused RoPE + head-split.
// =====================================================================
__global__ __launch_bounds__(256) void proj_qkv_mfma(
    const unsigned short* __restrict__ Xb, const unsigned short* __restrict__ Wt,
    unsigned short* __restrict__ qb, unsigned short* __restrict__ kb,
    unsigned short* __restrict__ vb)
{
    __shared__ __align__(16) unsigned short As[128 * 32];
    __shared__ __align__(16) unsigned short Bs[128 * 32];

    const int t     = threadIdx.x;
    const int w     = t >> 6, lane = t & 63;
    const int lane4 = lane & 15, quad = lane >> 4, quad8 = quad * 8;
    const int wm    = w >> 1, wn = w & 1;
    const int m0    = blockIdx.y * 128, n0 = blockIdx.x * 128;

    const int srow = t >> 2, scol = (t & 3) * 8;
    const unsigned short* gA = Xb + (size_t)(m0 + srow) * DD + scol;
    const unsigned short* gB = Wt + (size_t)(n0 + srow) * DD + scol;
    unsigned short* lA = As + t * 8;
    unsigned short* lB = Bs + t * 8;

    f32x4 acc[4][4] = {};

    for (int k0 = 0; k0 < DD; k0 += 32) {
        __syncthreads();
        ASYNC16(gA + k0,            lA);
        ASYNC16(gA + 64 * DD + k0,  lA + 2048);
        ASYNC16(gB + k0,            lB);
        ASYNC16(gB + 64 * DD + k0,  lB + 2048);
        __syncthreads();

        bf16x8 a[4], b[4];
        #pragma unroll
        for (int i = 0; i < 4; ++i)
            a[i] = *(const bf16x8*)&As[(wm * 64 + i * 16 + lane4) * 32 + quad8];
        #pragma unroll
        for (int j = 0; j < 4; ++j)
            b[j] = *(const bf16x8*)&Bs[(wn * 64 + j * 16 + lane4) * 32 + quad8];
        #pragma unroll
        for (int i = 0; i < 4; ++i)
            #pragma unroll
            for (int j = 0; j < 4; ++j)
                acc[i][j] = __builtin_amdgcn_mfma_f32_16x16x32_bf16(
                    a[i], b[j], acc[i][j], 0, 0, 0);
    }

    // ---- epilogue ----
    const int sec = n0 >> 10;                  // 0=q 1=k 2=v (uniform/block)

    if (sec == 2) {
        // V: transposed global layout, 4 consecutive n per lane -> uint2
        #pragma unroll
        for (int j = 0; j < 4; ++j) {
            const int csec = (n0 & 1023) + wn * 64 + j * 16;
            const int h    = csec >> 6;
            const int dh   = (csec & 63) + lane4;
            #pragma unroll
            for (int i = 0; i < 4; ++i) {
                const int rg0 = m0 + wm * 64 + i * 16 + quad * 4;
                const int b   = rg0 >> 11;
                const int n   = rg0 & 2047;
                uint2 pk;
                pk.x = packbf2(acc[i][j][0], acc[i][j][1]);
                pk.y = packbf2(acc[i][j][2], acc[i][j][3]);
                *(uint2*)(vb + (((size_t)b * HH + h) * DHD + dh) * NN + n) = pk;
            }
        }
    } else {
        unsigned short* dst = (sec == 0) ? qb : kb;
        const float qscale = (sec == 0) ? SCALE_LOG2E : 1.0f;
        #pragma unroll
        for (int j = 0; j < 4; ++j) {
            const int csec = (n0 & 1023) + wn * 64 + j * 16;
            const int h    = csec >> 6;
            const int dhb  = csec & 63;
            const int dh   = dhb + lane4;
            const bool rope = (dhb < 32);          // wave-uniform
            const float invf = fexp2(-(float)(dh >> 1) * LOG2_10K_D16);
            #pragma unroll
            for (int i = 0; i < 4; ++i) {
                #pragma unroll
                for (int r = 0; r < 4; ++r) {
                    const int rg = m0 + wm * 64 + i * 16 + quad * 4 + r;
                    const int b  = rg >> 11;
                    const int n  = rg & 2047;
                    float x = acc[i][j][r] * qscale;
                    if (rope) {
                        const float ang = (float)n * invf;
                        float s_, c_;
                        __sincosf(ang, &s_, &c_);
                        const float p = __shfl_xor(x, 1);
                        x = (lane4 & 1) ? fmaf(p, s_, x * c_)
                                        : fmaf(p, -s_, x * c_);
                    }
                    dst[(((size_t)b * HH + h) * NN + n) * DHD + dh] = f2bf(x);
                }
            }
        }
    }
}

// =====================================================================
// Kernel 2: flash attention, S^T formulation, max-free softmax.
// R3: software-pipelined LDS staging (T14 issue-early/write-late +
// double buffer, ONE barrier per tile). Global loads for tile kt+1
// are issued before computing tile kt and land in LDS after it --
// their latency hides under the full MFMA/exp phase instead of being
// exposed between back-to-back barriers (R1 structure).
// XCD pinning kept: id%8 == bh%8 -> K/V L2-resident (R1: FETCH 46MB).
// =====================================================================
__global__ __launch_bounds__(256) void attn_kernel(
    const unsigned short* __restrict__ qb, const unsigned short* __restrict__ kb,
    const unsigned short* __restrict__ vtb, unsigned short* __restrict__ aob)
{
    __shared__ __align__(16) unsigned short ks[2][64][72];   // [buf][key][dh]
    __shared__ __align__(16) unsigned short vs[2][64][72];   // [buf][dh][key]
    __shared__ __align__(16) unsigned short pst[4][16][72];  // per-wave P^T

    const int t     = threadIdx.x;
    const int w     = t >> 6;
    const int lane  = t & 63;
    const int lane4 = lane & 15;
    const int quad  = lane >> 4;
    const int quad8 = quad * 8;

    const int bid = blockIdx.x;
    const int bh  = bid & 63;          // id%8 = bh%8 -> per-XCD head groups
    const int q0  = (bid >> 6) * 64;
    const size_t hb = (size_t)bh * NN * DHD;

    // Q B-fragments (registers, whole kernel): B[n=q=lane4][k=dh quad8+j]
    const unsigned short* qrow = qb + hb + (size_t)(q0 + w * 16 + lane4) * DHD;
    const bf16x8 qf0 = *(const bf16x8*)(qrow + quad8);
    const bf16x8 qf1 = *(const bf16x8*)(qrow + 32 + quad8);

    // ones A-fragment for the l-accumulating MFMA
    bf16x8 onesf;
    #pragma unroll
    for (int j = 0; j < 8; ++j) onesf[j] = (short)0x3F80;

    // staging maps: chunk u in [0,512): row = u>>3, col = (u&7)*8
    const int rA = t >> 3,          cA = (t & 7) * 8;        // u = t
    const int rB = (t + 256) >> 3,  cB = cA;                 // u = t+256
    const unsigned short* kgA = kb  + hb + (size_t)rA * DHD + cA;
    const unsigned short* kgB = kb  + hb + (size_t)rB * DHD + cB;
    const unsigned short* vgA = vtb + hb + (size_t)rA * NN  + cA;
    const unsigned short* vgB = vtb + hb + (size_t)rB * NN  + cB;

    f32x4 o[4], lacc;
    #pragma unroll
    for (int c = 0; c < 4; ++c) o[c] = (f32x4){0.f, 0.f, 0.f, 0.f};
    lacc = (f32x4){0.f, 0.f, 0.f, 0.f};

    // ---- prologue: stage tile 0 into buf 0 ----
    {
        const bf16x8 k0v = *(const bf16x8*)(kgA);
        const bf16x8 k1v = *(const bf16x8*)(kgB);
        const bf16x8 v0v = *(const bf16x8*)(vgA);
        const bf16x8 v1v = *(const bf16x8*)(vgB);
        *(bf16x8*)&ks[0][rA][cA] = k0v;
        *(bf16x8*)&ks[0][rB][cB] = k1v;
        *(bf16x8*)&vs[0][rA][cA] = v0v;
        *(bf16x8*)&vs[0][rB][cB] = v1v;
    }
    __syncthreads();

    for (int kt = 0; kt < NN / 64; ++kt) {
        const int cur = kt & 1;
        const bool more = (kt + 1 < NN / 64);

        // ---- issue next tile's global loads (land during compute) ----
        bf16x8 nk0, nk1, nv0, nv1;
        if (more) {
            nk0 = *(const bf16x8*)(kgA + (size_t)(kt + 1) * 64 * DHD);
            nk1 = *(const bf16x8*)(kgB + (size_t)(kt + 1) * 64 * DHD);
            nv0 = *(const bf16x8*)(vgA + (kt + 1) * 64);
            nv1 = *(const bf16x8*)(vgB + (kt + 1) * 64);
        }

        // ---- S^T = K Q^T : 4 key-tiles, each K=64 over dh ----
        f32x4 sc[4];
        #pragma unroll
        for (int c = 0; c < 4; ++c) {
            const bf16x8 a0 = *(const bf16x8*)&ks[cur][c * 16 + lane4][quad8];
            const bf16x8 a1 = *(const bf16x8*)&ks[cur][c * 16 + lane4][32 + quad8];
            f32x4 z = (f32x4){0.f, 0.f, 0.f, 0.f};
            z = __builtin_amdgcn_mfma_f32_16x16x32_bf16(a0, qf0, z, 0, 0, 0);
            z = __builtin_amdgcn_mfma_f32_16x16x32_bf16(a1, qf1, z, 0, 0, 0);
            sc[c] = z;   // (key = c*16 + quad*4 + r, q = lane4)
        }

        // ---- max-free softmax numerators: p = exp2(sc), pack, store ----
        #pragma unroll
        for (int c = 0; c < 4; ++c) {
            const float p0 = fexp2(sc[c][0]);
            const float p1 = fexp2(sc[c][1]);
            const float p2 = fexp2(sc[c][2]);
            const float p3 = fexp2(sc[c][3]);
            uint2 pk;
            pk.x = packbf2(p0, p1);
            pk.y = packbf2(p2, p3);
            *(uint2*)&pst[w][lane4][c * 16 + quad * 4] = pk;
        }

        // ---- P^T B-fragments (wave-local LDS, no barrier) ----
        const bf16x8 pf0 = *(const bf16x8*)&pst[w][lane4][quad8];        // keys 0..31
        const bf16x8 pf1 = *(const bf16x8*)&pst[w][lane4][32 + quad8];   // keys 32..63

        // ---- O^T += V^T P^T ; l += ones P^T ----
        #pragma unroll
        for (int c = 0; c < 4; ++c) {
            const bf16x8 v0 = *(const bf16x8*)&vs[cur][c * 16 + lane4][quad8];
            const bf16x8 v1 = *(const bf16x8*)&vs[cur][c * 16 + lane4][32 + quad8];
            o[c] = __builtin_amdgcn_mfma_f32_16x16x32_bf16(v0, pf0, o[c], 0, 0, 0);
            o[c] = __builtin_amdgcn_mfma_f32_16x16x32_bf16(v1, pf1, o[c], 0, 0, 0);
        }
        lacc = __builtin_amdgcn_mfma_f32_16x16x32_bf16(onesf, pf0, lacc, 0, 0, 0);
        lacc = __builtin_amdgcn_mfma_f32_16x16x32_bf16(onesf, pf1, lacc, 0, 0, 0);

        // ---- write-late: staged regs -> other buffer (vmcnt satisfied) ----
        if (more) {
            *(bf16x8*)&ks[cur ^ 1][rA][cA] = nk0;
            *(bf16x8*)&ks[cur ^ 1][rB][cB] = nk1;
            *(bf16x8*)&vs[cur ^ 1][rA][cA] = nv0;
            *(bf16x8*)&vs[cur ^ 1][rB][cB] = nv1;
        }
        __syncthreads();   // single barrier per tile
    }

    // ---- epilogue: O^T (dh=c*16+quad*4+r, q=lane4), lane-local normalize ----
    const int b = bh >> 4, h = bh & 15;
    const float linv = 1.0f / lacc[0];
    const int n = q0 + w * 16 + lane4;
    unsigned short* obase = aob + ((size_t)b * NN + n) * INNER + h * DHD;
    #pragma unroll
    for (int c = 0; c < 4; ++c) {
        uint2 pk;
        pk.x = packbf2(o[c][0] * linv, o[c][1] * linv);
        pk.y = packbf2(o[c][2] * linv, o[c][3] * linv);
        *(uint2*)(obase + c * 16 + quad * 4) = pk;
    }
}

// =====================================================================
// Kernel 3: output projection via bf16 MFMA.
// =====================================================================
__global__ __launch_bounds__(256) void out_proj_mfma(
    const unsigned short* __restrict__ Ab, const unsigned short* __restrict__ Wt,
    const float* __restrict__ bias, float* __restrict__ C)
{
    __shared__ __align__(16) unsigned short As[128 * 32];
    __shared__ __align__(16) unsigned short Bs[128 * 32];

    const int t     = threadIdx.x;
    const int w     = t >> 6, lane = t & 63;
    const int lane4 = lane & 15, quad = lane >> 4, quad8 = quad * 8;
    const int wm    = w >> 1, wn = w & 1;
    const int m0    = blockIdx.y * 128, n0 = blockIdx.x * 128;

    const int srow = t >> 2, scol = (t & 3) * 8;
    const unsigned short* gA = Ab + (size_t)(m0 + srow) * INNER + scol;
    const unsigned short* gB = Wt + (size_t)(n0 + srow) * INNER + scol;
    unsigned short* lA = As + t * 8;
    unsigned short* lB = Bs + t * 8;

    f32x4 acc[4][4] = {};

    for (int k0 = 0; k0 < INNER; k0 += 32) {
        __syncthreads();
        ASYNC16(gA + k0,               lA);
        ASYNC16(gA + 64 * INNER + k0,  lA + 2048);
        ASYNC16(gB + k0,               lB);
        ASYNC16(gB + 64 * INNER + k0,  lB + 2048);
        __syncthreads();

        bf16x8 a[4], b[4];
        #pragma unroll
        for (int i = 0; i < 4; ++i)
            a[i] = *(const bf16x8*)&As[(wm * 64 + i * 16 + lane4) * 32 + quad8];
        #pragma unroll
        for (int j = 0; j < 4; ++j)
            b[j] = *(const bf16x8*)&Bs[(wn * 64 + j * 16 + lane4) * 32 + quad8];
        #pragma unroll
        for (int i = 0; i < 4; ++i)
            #pragma unroll
            for (int j = 0; j < 4; ++j)
                acc[i][j] = __builtin_amdgcn_mfma_f32_16x16x32_bf16(
                    a[i], b[j], acc[i][j], 0, 0, 0);
    }

    #pragma unroll
    for (int j = 0; j < 4; ++j) {
        const int col = n0 + wn * 64 + j * 16 + lane4;
        const float bv = bias[col];
        #pragma unroll
        for (int i = 0; i < 4; ++i)
            #pragma unroll
            for (int r = 0; r < 4; ++r) {
                const int rg = m0 + wm * 64 + i * 16 + quad * 4 + r;
                C[(size_t)rg * DD + col] = acc[i][j][r] + bv;
            }
    }
}

// =====================================================================
extern "C" void kernel_launch(void* const* d_in, const int* in_sizes, int n_in,
                              void* d_out, int out_size, void* d_ws, size_t ws_size,
                              hipStream_t stream)
{
    const float* X    = (const float*)d_in[0];   // (4,2048,1024)
    const float* Wq   = (const float*)d_in[1];   // (1024,1024)
    const float* Wkv  = (const float*)d_in[2];   // (1024,2048)
    const float* Wout = (const float*)d_in[3];   // (1024,1024)
    const float* bout = (const float*)d_in[4];   // (1024,)
    float* out = (float*)d_out;

    // ws (bf16 elems): qb|kb|vtb|xb(=aob after proj)|WtAll|WoT = 75.5 MB
    const size_t E = (size_t)BB * HH * NN * DHD;   // 8388608
    unsigned short* qb  = (unsigned short*)d_ws;
    unsigned short* kb  = qb + E;
    unsigned short* vtb = kb + E;                // V^T [b][h][dh][n]
    unsigned short* xb  = vtb + E;               // X bf16; later reused as ao
    unsigned short* wt  = xb + E;                // [3072][1024] = WqT ; WkvT
    unsigned short* wo  = wt + (size_t)3072 * 1024;  // [1024][1024]

    cast_x_kernel<<<4096, 256, 0, stream>>>(X, xb);
    tcast_kernel<<<dim3(32, 32), 256, 0, stream>>>(Wq,   wt,               1024, 1024);
    tcast_kernel<<<dim3(64, 32), 256, 0, stream>>>(Wkv,  wt + 1024 * 1024, 1024, 2048);
    tcast_kernel<<<dim3(32, 32), 256, 0, stream>>>(Wout, wo,               1024, 1024);

    proj_qkv_mfma<<<dim3(3072 / 128, 8192 / 128), 256, 0, stream>>>(
        xb, wt, qb, kb, vtb);

    attn_kernel<<<dim3(NN / 64 * BB * HH), 256, 0, stream>>>(qb, kb, vtb, xb);

    out_proj_mfma<<<dim3(1024 / 128, 8192 / 128), 256, 0, stream>>>(
        xb, wo, bout, out);
}

// Round 4
// 299.174 us; speedup vs baseline: 2.1764x; 1.0774x over previous
//
#include <hip/hip_runtime.h>
#include <math.h>

// Problem constants (fixed by reference: b=4, n=2048, d=1024, H=16, DH=64)
#define BB    4
#define NN    2048
#define DD    1024
#define HH    16
#define DHD   64
#define INNER 1024
// log2(10000)/16 for inv_freq = 2^(-f * LOG2_10K_D16)
#define LOG2_10K_D16 0.8304820237218406f
// SCALE * log2(e): folded into Q at projection time -> attn uses raw exp2
#define SCALE_LOG2E 0.1803368801111601f

typedef short bf16x8 __attribute__((ext_vector_type(8)));   // 8 bf16 = 4 VGPRs
typedef short bf16x4 __attribute__((ext_vector_type(4)));   // 4 bf16 = 2 VGPRs
typedef float f32x4  __attribute__((ext_vector_type(4)));
typedef unsigned short u16x8 __attribute__((ext_vector_type(8)));

// async 16B/lane global->LDS (lane i lands at wave-uniform base + i*16)
#define ASYNC16(g, l) __builtin_amdgcn_global_load_lds( \
    (const __attribute__((address_space(1))) void*)(g),  \
    (__attribute__((address_space(3))) void*)(l), 16, 0, 0)

#define MFMA16(a, b, c) __builtin_amdgcn_mfma_f32_16x16x32_bf16((a), (b), (c), 0, 0, 0)

// ---------- fast exp2: raw v_exp_f32, no libm range guard ----------
static __device__ __forceinline__ float fexp2(float x) {
#if __has_builtin(__builtin_amdgcn_exp2f)
    return __builtin_amdgcn_exp2f(x);
#else
    float r;
    asm("v_exp_f32 %0, %1" : "=v"(r) : "v"(x));
    return r;
#endif
}

// ---------- bf16 helpers (manual RNE; no hip_bf16.h dependency) ----------
static __device__ __forceinline__ unsigned short f2bf(float f) {
    union { float f; unsigned int u; } v; v.f = f;
    unsigned int u = v.u;
    u += 0x7fffu + ((u >> 16) & 1u);
    return (unsigned short)(u >> 16);
}
// pack two f32 -> bf16x2 dword, round-half-up via +0x8000 then byte-perm.
static __device__ __forceinline__ unsigned int packbf2(float lo, float hi) {
    union { float f; unsigned int u; } a, b;
    a.f = lo; b.f = hi;
    return __builtin_amdgcn_perm(b.u + 0x8000u, a.u + 0x8000u, 0x07060302u);
}

// =====================================================================
// Pre-pass A: cast X fp32 -> bf16
// =====================================================================
__global__ __launch_bounds__(256) void cast_x_kernel(
    const float* __restrict__ X, unsigned short* __restrict__ Xb)
{
    const size_t i = ((size_t)blockIdx.x * 256 + threadIdx.x) * 8;
    const float4 a = *(const float4*)(X + i);
    const float4 b = *(const float4*)(X + i + 4);
    u16x8 o;
    o[0] = f2bf(a.x); o[1] = f2bf(a.y); o[2] = f2bf(a.z); o[3] = f2bf(a.w);
    o[4] = f2bf(b.x); o[5] = f2bf(b.y); o[6] = f2bf(b.z); o[7] = f2bf(b.w);
    *(u16x8*)(Xb + i) = o;
}

// =====================================================================
// Pre-pass B: transpose-cast W [K][N] fp32 -> Wt [N][K] bf16
// =====================================================================
__global__ __launch_bounds__(256) void tcast_kernel(
    const float* __restrict__ src, unsigned short* __restrict__ dst,
    int K, int N)
{
    __shared__ float ts[32][33];
    const int t = threadIdx.x;
    const int n0 = blockIdx.x * 32, k0 = blockIdx.y * 32;
    const int r = t >> 5, c = t & 31;
    #pragma unroll
    for (int p = 0; p < 4; ++p)
        ts[r + p * 8][c] = src[(size_t)(k0 + r + p * 8) * N + n0 + c];
    __syncthreads();
    #pragma unroll
    for (int p = 0; p < 4; ++p)
        dst[(size_t)(n0 + r + p * 8) * K + k0 + c] = f2bf(ts[c][r + p * 8]);
}

// =====================================================================
// Kernel 1: QKV projection via bf16 MFMA + fused RoPE + head-split.
// =====================================================================
__global__ __launch_bounds__(256) void proj_qkv_mfma(
    const unsigned short* __restrict__ Xb, const unsigned short* __restrict__ Wt,
    unsigned short* __restrict__ qb, unsigned short* __restrict__ kb,
    unsigned short* __restrict__ vb)
{
    __shared__ __align__(16) unsigned short As[128 * 32];
    __shared__ __align__(16) unsigned short Bs[128 * 32];

    const int t     = threadIdx.x;
    const int w     = t >> 6, lane = t & 63;
    const int lane4 = lane & 15, quad = lane >> 4, quad8 = quad * 8;
    const int wm    = w >> 1, wn = w & 1;
    const int m0    = blockIdx.y * 128, n0 = blockIdx.x * 128;

    const int srow = t >> 2, scol = (t & 3) * 8;
    const unsigned short* gA = Xb + (size_t)(m0 + srow) * DD + scol;
    const unsigned short* gB = Wt + (size_t)(n0 + srow) * DD + scol;
    unsigned short* lA = As + t * 8;
    unsigned short* lB = Bs + t * 8;

    f32x4 acc[4][4] = {};

    for (int k0 = 0; k0 < DD; k0 += 32) {
        __syncthreads();
        ASYNC16(gA + k0,            lA);
        ASYNC16(gA + 64 * DD + k0,  lA + 2048);
        ASYNC16(gB + k0,            lB);
        ASYNC16(gB + 64 * DD + k0,  lB + 2048);
        __syncthreads();

        bf16x8 a[4], b[4];
        #pragma unroll
        for (int i = 0; i < 4; ++i)
            a[i] = *(const bf16x8*)&As[(wm * 64 + i * 16 + lane4) * 32 + quad8];
        #pragma unroll
        for (int j = 0; j < 4; ++j)
            b[j] = *(const bf16x8*)&Bs[(wn * 64 + j * 16 + lane4) * 32 + quad8];
        #pragma unroll
        for (int i = 0; i < 4; ++i)
            #pragma unroll
            for (int j = 0; j < 4; ++j)
                acc[i][j] = MFMA16(a[i], b[j], acc[i][j]);
    }

    // ---- epilogue ----
    const int sec = n0 >> 10;                  // 0=q 1=k 2=v (uniform/block)

    if (sec == 2) {
        // V: transposed global layout, 4 consecutive n per lane -> uint2
        #pragma unroll
        for (int j = 0; j < 4; ++j) {
            const int csec = (n0 & 1023) + wn * 64 + j * 16;
            const int h    = csec >> 6;
            const int dh   = (csec & 63) + lane4;
            #pragma unroll
            for (int i = 0; i < 4; ++i) {
                const int rg0 = m0 + wm * 64 + i * 16 + quad * 4;
                const int b   = rg0 >> 11;
                const int n   = rg0 & 2047;
                uint2 pk;
                pk.x = packbf2(acc[i][j][0], acc[i][j][1]);
                pk.y = packbf2(acc[i][j][2], acc[i][j][3]);
                *(uint2*)(vb + (((size_t)b * HH + h) * DHD + dh) * NN + n) = pk;
            }
        }
    } else {
        unsigned short* dst = (sec == 0) ? qb : kb;
        const float qscale = (sec == 0) ? SCALE_LOG2E : 1.0f;
        #pragma unroll
        for (int j = 0; j < 4; ++j) {
            const int csec = (n0 & 1023) + wn * 64 + j * 16;
            const int h    = csec >> 6;
            const int dhb  = csec & 63;
            const int dh   = dhb + lane4;
            const bool rope = (dhb < 32);          // wave-uniform
            const float invf = fexp2(-(float)(dh >> 1) * LOG2_10K_D16);
            #pragma unroll
            for (int i = 0; i < 4; ++i) {
                #pragma unroll
                for (int r = 0; r < 4; ++r) {
                    const int rg = m0 + wm * 64 + i * 16 + quad * 4 + r;
                    const int b  = rg >> 11;
                    const int n  = rg & 2047;
                    float x = acc[i][j][r] * qscale;
                    if (rope) {
                        const float ang = (float)n * invf;
                        float s_, c_;
                        __sincosf(ang, &s_, &c_);
                        const float p = __shfl_xor(x, 1);
                        x = (lane4 & 1) ? fmaf(p, s_, x * c_)
                                        : fmaf(p, -s_, x * c_);
                    }
                    dst[(((size_t)b * HH + h) * NN + n) * DHD + dh] = f2bf(x);
                }
            }
        }
    }
}

// =====================================================================
// Kernel 2: flash attention, KEY-SPLIT waves (R4).
// Diagnosis R1-R3: kernel is LDS-pipe bound (~59% LDS cycles + 27%
// bank-conflict cycles; invariant to HBM/occupancy/barriers).
// New structure: wave kq owns key-quarter; Q-frags for all 64 queries
// live in registers. S^T MFMA output layout (key=quad*4+r, q=lane4)
// IS the PV B-fragment layout for the wave's own keys -> P stays in
// registers (pst LDS buffer eliminated). ks/vs fragment reads shrink
// 4x (no cross-wave redundancy). 128 keys/iter so PV contraction=32.
// V stored column-permuted (key -> c*32+quad*8+sub*4+r) so each PV
// A-frag is one b128. All tiles XOR-slot-swizzled at exact stride
// (uniform bank-touch floor), total LDS = 64 KB.
// Per-wave partial O (64x64, over its 32 keys/iter) is reduced across
// the 4 waves ONCE at the end via an LDS overlay.
// XCD pinning kept: id%8 == bh%8 -> K/V L2-resident.
// =====================================================================
__global__ __launch_bounds__(256, 2) void attn_kernel(
    const unsigned short* __restrict__ qb, const unsigned short* __restrict__ kb,
    const unsigned short* __restrict__ vtb, unsigned short* __restrict__ aob)
{
    __shared__ __align__(16) unsigned char smem[65536];
    unsigned short (*ks)[128][64] = (unsigned short (*)[128][64])smem;          // 2x16KB
    unsigned short (*vs)[64][128] = (unsigned short (*)[64][128])(smem + 32768); // 2x16KB

    const int t     = threadIdx.x;
    const int kq    = t >> 6;          // wave's key-quarter
    const int lane  = t & 63;
    const int lane4 = lane & 15;
    const int quad  = lane >> 4;
    const int quad8 = quad * 8;
    const int l7    = lane4 & 7;

    const int bid = blockIdx.x;
    const int bh  = bid & 63;          // id%8 = bh%8 -> per-XCD head groups
    const int q0  = (bid >> 6) * 64;
    const size_t hb = (size_t)bh * NN * DHD;

    // Q B-fragments for ALL 64 queries (held in registers whole kernel)
    bf16x8 qf[4][2];
    #pragma unroll
    for (int qt = 0; qt < 4; ++qt) {
        const unsigned short* qrow = qb + hb + (size_t)(q0 + qt * 16 + lane4) * DHD;
        qf[qt][0] = *(const bf16x8*)(qrow + quad8);
        qf[qt][1] = *(const bf16x8*)(qrow + 32 + quad8);
    }

    // ones A-fragment for the l-accumulating MFMA
    bf16x8 onesf;
    #pragma unroll
    for (int j = 0; j < 8; ++j) onesf[j] = (short)0x3F80;

    // ---- staging geometry (all XOR swizzles are s-invariant) ----
    // K: chunk u=t+256s: row=(t>>3)+32s, gcol=(t&7)*8, slot'=(t&7)^((t>>3)&7)
    const int krow0 = t >> 3;
    const int kcol  = ((t & 7) ^ (krow0 & 7)) * 8;
    const unsigned short* kg = kb + hb + (size_t)krow0 * DHD + (t & 7) * 8;
    // V: chunk u=t+256s: row=(t>>4)+16s, m=t&15, gcol=m*8
    //    keys 8m..8m+7 -> permuted cols: slotA(e<4), slotB(e>=4), +sub*4
    const int vrow0 = t >> 4;
    const int vm    = t & 15;
    const int vr7   = vrow0 & 7;
    const int vcX   = (vm >> 1) & 3;
    const int vsub  = vm >> 3;
    const int vqA   = (2 * vm) & 3;
    const int vqB   = (2 * vm + 1) & 3;
    const int colA  = (((vcX * 4 + vqA) ^ vr7) * 8) + vsub * 4;
    const int colB  = (((vcX * 4 + vqB) ^ vr7) * 8) + vsub * 4;
    const unsigned short* vg = vtb + hb + (size_t)vrow0 * NN + vm * 8;

    f32x4 o[4][4], lacc[4];
    #pragma unroll
    for (int d = 0; d < 4; ++d)
        #pragma unroll
        for (int qt = 0; qt < 4; ++qt) o[d][qt] = (f32x4){0.f, 0.f, 0.f, 0.f};
    #pragma unroll
    for (int qt = 0; qt < 4; ++qt) lacc[qt] = (f32x4){0.f, 0.f, 0.f, 0.f};

    // ---- prologue: stage tile 0 into buf 0 ----
    {
        bf16x8 kv[4], vv[4];
        #pragma unroll
        for (int s = 0; s < 4; ++s) {
            kv[s] = *(const bf16x8*)(kg + (size_t)s * 32 * DHD);
            vv[s] = *(const bf16x8*)(vg + (size_t)s * 16 * NN);
        }
        #pragma unroll
        for (int s = 0; s < 4; ++s) {
            *(bf16x8*)&ks[0][krow0 + 32 * s][kcol] = kv[s];
            bf16x4 lo = __builtin_shufflevector(vv[s], vv[s], 0, 1, 2, 3);
            bf16x4 hi = __builtin_shufflevector(vv[s], vv[s], 4, 5, 6, 7);
            *(bf16x4*)&vs[0][vrow0 + 16 * s][colA] = lo;
            *(bf16x4*)&vs[0][vrow0 + 16 * s][colB] = hi;
        }
    }
    __syncthreads();

    for (int kt = 0; kt < NN / 128; ++kt) {
        const int cur = kt & 1;
        const bool more = (kt + 1 < NN / 128);

        // issue next tile's global loads (latency hides under compute)
        bf16x8 kv[4], vv[4];
        if (more) {
            #pragma unroll
            for (int s = 0; s < 4; ++s) {
                kv[s] = *(const bf16x8*)(kg + (size_t)(kt + 1) * 128 * DHD + (size_t)s * 32 * DHD);
                vv[s] = *(const bf16x8*)(vg + (kt + 1) * 128 + (size_t)s * 16 * NN);
            }
        }

        // ---- QK A-fragments: this wave's 16 keys per 64-key subtile ----
        bf16x8 ak[2][2];
        #pragma unroll
        for (int sub = 0; sub < 2; ++sub) {
            const int row = sub * 64 + kq * 16 + lane4;
            ak[sub][0] = *(const bf16x8*)&ks[cur][row][(quad ^ l7) * 8];
            ak[sub][1] = *(const bf16x8*)&ks[cur][row][((quad + 4) ^ l7) * 8];
        }

        // ---- S^T -> exp2 -> P B-frags, all in registers ----
        bf16x8 pb[4];
        #pragma unroll
        for (int qt = 0; qt < 4; ++qt) {
            f32x4 z0 = (f32x4){0.f, 0.f, 0.f, 0.f};
            f32x4 z1 = (f32x4){0.f, 0.f, 0.f, 0.f};
            z0 = MFMA16(ak[0][0], qf[qt][0], z0);
            z0 = MFMA16(ak[0][1], qf[qt][1], z0);
            z1 = MFMA16(ak[1][0], qf[qt][0], z1);
            z1 = MFMA16(ak[1][1], qf[qt][1], z1);
            union { unsigned int u[4]; bf16x8 v; } pk;
            pk.u[0] = packbf2(fexp2(z0[0]), fexp2(z0[1]));
            pk.u[1] = packbf2(fexp2(z0[2]), fexp2(z0[3]));
            pk.u[2] = packbf2(fexp2(z1[0]), fexp2(z1[1]));
            pk.u[3] = packbf2(fexp2(z1[2]), fexp2(z1[3]));
            pb[qt] = pk.v;
            lacc[qt] = MFMA16(onesf, pb[qt], lacc[qt]);   // l partial (wave's keys)
        }

        // ---- O^T += V^T P^T over this wave's 32 keys ----
        #pragma unroll
        for (int d = 0; d < 4; ++d) {
            const bf16x8 av = *(const bf16x8*)&vs[cur][d * 16 + lane4][((kq * 4 + quad) ^ l7) * 8];
            #pragma unroll
            for (int qt = 0; qt < 4; ++qt)
                o[d][qt] = MFMA16(av, pb[qt], o[d][qt]);
        }

        // ---- write-late: staged regs -> other buffer ----
        if (more) {
            #pragma unroll
            for (int s = 0; s < 4; ++s) {
                *(bf16x8*)&ks[cur ^ 1][krow0 + 32 * s][kcol] = kv[s];
                bf16x4 lo = __builtin_shufflevector(vv[s], vv[s], 0, 1, 2, 3);
                bf16x4 hi = __builtin_shufflevector(vv[s], vv[s], 4, 5, 6, 7);
                *(bf16x4*)&vs[cur ^ 1][vrow0 + 16 * s][colA] = lo;
                *(bf16x4*)&vs[cur ^ 1][vrow0 + 16 * s][colB] = hi;
            }
        }
        __syncthreads();
    }

    // ---- epilogue: cross-wave O reduction via LDS overlay ----
    float* pbuf = (float*)smem;   // [w][dh 64][q 64] f32 = 64 KB
    #pragma unroll
    for (int d = 0; d < 4; ++d)
        #pragma unroll
        for (int qt = 0; qt < 4; ++qt)
            #pragma unroll
            for (int r = 0; r < 4; ++r)
                pbuf[(kq * 64 + d * 16 + quad * 4 + r) * 64 + qt * 16 + lane4] = o[d][qt][r];
    __syncthreads();

    // wave kq finalizes q-tile kq (all dh)
    f32x4 of[4];
    #pragma unroll
    for (int d = 0; d < 4; ++d)
        #pragma unroll
        for (int r = 0; r < 4; ++r) {
            const int dh = d * 16 + quad * 4 + r;
            const int qc = kq * 16 + lane4;
            of[d][r] = pbuf[dh * 64 + qc] + pbuf[(64 + dh) * 64 + qc]
                     + pbuf[(128 + dh) * 64 + qc] + pbuf[(192 + dh) * 64 + qc];
        }
    __syncthreads();

    // l exchange (reuse first 1 KB of the overlay after O is consumed)
    if (quad == 0) {
        #pragma unroll
        for (int qt = 0; qt < 4; ++qt)
            pbuf[(kq * 4 + qt) * 16 + lane4] = lacc[qt][0];
    }
    __syncthreads();
    const float lt = pbuf[(0 * 4 + kq) * 16 + lane4] + pbuf[(1 * 4 + kq) * 16 + lane4]
                   + pbuf[(2 * 4 + kq) * 16 + lane4] + pbuf[(3 * 4 + kq) * 16 + lane4];
    const float linv = 1.0f / lt;

    const int b = bh >> 4, h = bh & 15;
    const int n = q0 + kq * 16 + lane4;
    unsigned short* obase = aob + ((size_t)b * NN + n) * INNER + h * DHD;
    #pragma unroll
    for (int d = 0; d < 4; ++d) {
        uint2 pk;
        pk.x = packbf2(of[d][0] * linv, of[d][1] * linv);
        pk.y = packbf2(of[d][2] * linv, of[d][3] * linv);
        *(uint2*)(obase + d * 16 + quad * 4) = pk;
    }
}

// =====================================================================
// Kernel 3: output projection via bf16 MFMA.
// =====================================================================
__global__ __launch_bounds__(256) void out_proj_mfma(
    const unsigned short* __restrict__ Ab, const unsigned short* __restrict__ Wt,
    const float* __restrict__ bias, float* __restrict__ C)
{
    __shared__ __align__(16) unsigned short As[128 * 32];
    __shared__ __align__(16) unsigned short Bs[128 * 32];

    const int t     = threadIdx.x;
    const int w     = t >> 6, lane = t & 63;
    const int lane4 = lane & 15, quad = lane >> 4, quad8 = quad * 8;
    const int wm    = w >> 1, wn = w & 1;
    const int m0    = blockIdx.y * 128, n0 = blockIdx.x * 128;

    const int srow = t >> 2, scol = (t & 3) * 8;
    const unsigned short* gA = Ab + (size_t)(m0 + srow) * INNER + scol;
    const unsigned short* gB = Wt + (size_t)(n0 + srow) * INNER + scol;
    unsigned short* lA = As + t * 8;
    unsigned short* lB = Bs + t * 8;

    f32x4 acc[4][4] = {};

    for (int k0 = 0; k0 < INNER; k0 += 32) {
        __syncthreads();
        ASYNC16(gA + k0,               lA);
        ASYNC16(gA + 64 * INNER + k0,  lA + 2048);
        ASYNC16(gB + k0,               lB);
        ASYNC16(gB + 64 * INNER + k0,  lB + 2048);
        __syncthreads();

        bf16x8 a[4], b[4];
        #pragma unroll
        for (int i = 0; i < 4; ++i)
            a[i] = *(const bf16x8*)&As[(wm * 64 + i * 16 + lane4) * 32 + quad8];
        #pragma unroll
        for (int j = 0; j < 4; ++j)
            b[j] = *(const bf16x8*)&Bs[(wn * 64 + j * 16 + lane4) * 32 + quad8];
        #pragma unroll
        for (int i = 0; i < 4; ++i)
            #pragma unroll
            for (int j = 0; j < 4; ++j)
                acc[i][j] = MFMA16(a[i], b[j], acc[i][j]);
    }

    #pragma unroll
    for (int j = 0; j < 4; ++j) {
        const int col = n0 + wn * 64 + j * 16 + lane4;
        const float bv = bias[col];
        #pragma unroll
        for (int i = 0; i < 4; ++i)
            #pragma unroll
            for (int r = 0; r < 4; ++r) {
                const int rg = m0 + wm * 64 + i * 16 + quad * 4 + r;
                C[(size_t)rg * DD + col] = acc[i][j][r] + bv;
            }
    }
}

// =====================================================================
extern "C" void kernel_launch(void* const* d_in, const int* in_sizes, int n_in,
                              void* d_out, int out_size, void* d_ws, size_t ws_size,
                              hipStream_t stream)
{
    const float* X    = (const float*)d_in[0];   // (4,2048,1024)
    const float* Wq   = (const float*)d_in[1];   // (1024,1024)
    const float* Wkv  = (const float*)d_in[2];   // (1024,2048)
    const float* Wout = (const float*)d_in[3];   // (1024,1024)
    const float* bout = (const float*)d_in[4];   // (1024,)
    float* out = (float*)d_out;

    // ws (bf16 elems): qb|kb|vtb|xb(=aob after proj)|WtAll|WoT = 75.5 MB
    const size_t E = (size_t)BB * HH * NN * DHD;   // 8388608
    unsigned short* qb  = (unsigned short*)d_ws;
    unsigned short* kb  = qb + E;
    unsigned short* vtb = kb + E;                // V^T [b][h][dh][n]
    unsigned short* xb  = vtb + E;               // X bf16; later reused as ao
    unsigned short* wt  = xb + E;                // [3072][1024] = WqT ; WkvT
    unsigned short* wo  = wt + (size_t)3072 * 1024;  // [1024][1024]

    cast_x_kernel<<<4096, 256, 0, stream>>>(X, xb);
    tcast_kernel<<<dim3(32, 32), 256, 0, stream>>>(Wq,   wt,               1024, 1024);
    tcast_kernel<<<dim3(64, 32), 256, 0, stream>>>(Wkv,  wt + 1024 * 1024, 1024, 2048);
    tcast_kernel<<<dim3(32, 32), 256, 0, stream>>>(Wout, wo,               1024, 1024);

    proj_qkv_mfma<<<dim3(3072 / 128, 8192 / 128), 256, 0, stream>>>(
        xb, wt, qb, kb, vtb);

    attn_kernel<<<dim3(NN / 64 * BB * HH), 256, 0, stream>>>(qb, kb, vtb, xb);

    out_proj_mfma<<<dim3(1024 / 128, 8192 / 128), 256, 0, stream>>>(
        xb, wo, bout, out);
}